// Round 1
// baseline (5667.639 us; speedup 1.0000x reference)
//
#include <hip/hip_runtime.h>
#include <math.h>

// Problem constants (from reference): B=4, S=2048, H=1024, nh=16, dh=64.
#define BATCH 4
#define SEQ   2048
#define HID   1024
#define NH    16
#define DH    64
#define MTOT  (BATCH * SEQ)   // 8192
#define FILLV (-1e13f)

// ---------------------------------------------------------------------------
// GEMM: Y[M,N] = A[M,K] @ W[N,K]^T + bias[N]   (both A and W are K-contiguous)
// 128x128 tile, BK=16, 256 threads, 8x8 per-thread micro-tile.
// ---------------------------------------------------------------------------
#define BM 128
#define BN 128
#define BK 16

__global__ __launch_bounds__(256) void gemm_nt_bias(
    const float* __restrict__ A,    // [M,K]
    const float* __restrict__ W,    // [N,K]
    const float* __restrict__ bias, // [N]
    float* __restrict__ Y,          // [M,N]
    int M, int N, int K)
{
    __shared__ float As[BK][BM + 4];
    __shared__ float Bs[BK][BN + 4];

    const int tid = threadIdx.x;
    const int tx  = tid & 15;   // N direction, 0..15
    const int ty  = tid >> 4;   // M direction, 0..15
    const int m0  = blockIdx.y * BM;
    const int n0  = blockIdx.x * BN;

    float acc[8][8];
#pragma unroll
    for (int i = 0; i < 8; i++)
#pragma unroll
        for (int j = 0; j < 8; j++) acc[i][j] = 0.f;

    // staging loader: thread -> (row = tid/4 [0..63], k-chunk = (tid%4)*4)
    const int lrow = tid >> 2;
    const int lk4  = (tid & 3) * 4;

    for (int k0 = 0; k0 < K; k0 += BK) {
#pragma unroll
        for (int rr = 0; rr < 2; rr++) {
            const int row = lrow + rr * 64;
            const float4 av = *(const float4*)&A[(size_t)(m0 + row) * K + k0 + lk4];
            As[lk4 + 0][row] = av.x;
            As[lk4 + 1][row] = av.y;
            As[lk4 + 2][row] = av.z;
            As[lk4 + 3][row] = av.w;
            const float4 wv = *(const float4*)&W[(size_t)(n0 + row) * K + k0 + lk4];
            Bs[lk4 + 0][row] = wv.x;
            Bs[lk4 + 1][row] = wv.y;
            Bs[lk4 + 2][row] = wv.z;
            Bs[lk4 + 3][row] = wv.w;
        }
        __syncthreads();

#pragma unroll
        for (int kk = 0; kk < BK; kk++) {
            const float4 a0 = *(const float4*)&As[kk][ty * 4];
            const float4 a1 = *(const float4*)&As[kk][ty * 4 + 64];
            const float4 b0 = *(const float4*)&Bs[kk][tx * 4];
            const float4 b1 = *(const float4*)&Bs[kk][tx * 4 + 64];
            const float a[8] = {a0.x, a0.y, a0.z, a0.w, a1.x, a1.y, a1.z, a1.w};
            const float b[8] = {b0.x, b0.y, b0.z, b0.w, b1.x, b1.y, b1.z, b1.w};
#pragma unroll
            for (int i = 0; i < 8; i++)
#pragma unroll
                for (int j = 0; j < 8; j++)
                    acc[i][j] = fmaf(a[i], b[j], acc[i][j]);
        }
        __syncthreads();
    }

    // epilogue: bias + coalesced float4 stores
#pragma unroll
    for (int i = 0; i < 8; i++) {
        const int r = m0 + ((i < 4) ? (ty * 4 + i) : (64 + ty * 4 + (i - 4)));
#pragma unroll
        for (int jj = 0; jj < 2; jj++) {
            const int c = n0 + tx * 4 + jj * 64;
            float4 o;
            o.x = acc[i][jj * 4 + 0] + bias[c + 0];
            o.y = acc[i][jj * 4 + 1] + bias[c + 1];
            o.z = acc[i][jj * 4 + 2] + bias[c + 2];
            o.w = acc[i][jj * 4 + 3] + bias[c + 3];
            *(float4*)&Y[(size_t)r * N + c] = o;
        }
    }
}

// ---------------------------------------------------------------------------
// Flash-style causal attention with padding mask.
// One block = one (b, h, 64-query tile). 256 threads (16x16), 64-key tiles.
// Q/K/V stored as [B*S, H] with head h occupying cols [h*64, h*64+64).
// ---------------------------------------------------------------------------
#define TQ 64
#define TK 64
#define SPAD 68   // 64 + 4: keeps float4 alignment, breaks pow-2 bank stride

__device__ __forceinline__ float dot4(const float4 a, const float4 b) {
    return fmaf(a.x, b.x, fmaf(a.y, b.y, fmaf(a.z, b.z, a.w * b.w)));
}

__device__ __forceinline__ void fma4(float4& o, const float p, const float4 v) {
    o.x = fmaf(p, v.x, o.x);
    o.y = fmaf(p, v.y, o.y);
    o.z = fmaf(p, v.z, o.z);
    o.w = fmaf(p, v.w, o.w);
}

__global__ __launch_bounds__(256) void attn_causal(
    const float* __restrict__ Q,
    const float* __restrict__ Km,
    const float* __restrict__ Vm,
    const float* __restrict__ mask,  // [B,S] over KEY positions
    float* __restrict__ O)
{
    __shared__ float Qs[TQ][SPAD];
    __shared__ float Ks[TK][SPAD];
    __shared__ float Vs[TK][SPAD];
    __shared__ float Ss[TQ][SPAD];
    __shared__ float mrow[TQ], lrow[TQ], arow[TQ], mk[TK];

    const int tid = threadIdx.x;
    const int tx  = tid & 15;
    const int ty  = tid >> 4;
    const int qi  = blockIdx.x;
    const int h   = blockIdx.y;
    const int b   = blockIdx.z;
    const int q0  = qi * TQ;
    const float scale = 0.125f;  // 1/sqrt(64)

    // load Q tile, pre-scaled
    const size_t baseQ = ((size_t)b * SEQ + q0) * HID + (size_t)h * DH;
#pragma unroll
    for (int i = 0; i < 4; i++) {
        const int idx = tid + 256 * i;   // 0..1023 float4 slots
        const int r   = idx >> 4;
        const int d4  = (idx & 15) * 4;
        float4 qv = *(const float4*)&Q[baseQ + (size_t)r * HID + d4];
        qv.x *= scale; qv.y *= scale; qv.z *= scale; qv.w *= scale;
        *(float4*)&Qs[r][d4] = qv;
    }
    if (tid < TQ) { mrow[tid] = -INFINITY; lrow[tid] = 0.f; }

    float4 o[4];
#pragma unroll
    for (int i = 0; i < 4; i++) o[i] = make_float4(0.f, 0.f, 0.f, 0.f);

    for (int j = 0; j <= qi; j++) {
        const int k0 = j * TK;
        const size_t baseK = ((size_t)b * SEQ + k0) * HID + (size_t)h * DH;

        __syncthreads();  // previous iteration's Ss/Vs reads complete
#pragma unroll
        for (int i = 0; i < 4; i++) {
            const int idx = tid + 256 * i;
            const int r   = idx >> 4;
            const int d4  = (idx & 15) * 4;
            *(float4*)&Ks[r][d4] = *(const float4*)&Km[baseK + (size_t)r * HID + d4];
            *(float4*)&Vs[r][d4] = *(const float4*)&Vm[baseK + (size_t)r * HID + d4];
        }
        if (tid < TK) mk[tid] = mask[(size_t)b * SEQ + k0 + tid];
        __syncthreads();

        // scores: s[i][jj] = Qs[ty*4+i][:] . Ks[tx*4+jj][:]
        float s[4][4] = {{0.f}};
#pragma unroll
        for (int k4 = 0; k4 < DH; k4 += 4) {
            float4 qv[4], kv[4];
#pragma unroll
            for (int i = 0; i < 4; i++) qv[i] = *(const float4*)&Qs[ty * 4 + i][k4];
#pragma unroll
            for (int jj = 0; jj < 4; jj++) kv[jj] = *(const float4*)&Ks[tx * 4 + jj][k4];
#pragma unroll
            for (int i = 0; i < 4; i++)
#pragma unroll
                for (int jj = 0; jj < 4; jj++)
                    s[i][jj] += dot4(qv[i], kv[jj]);
        }
#pragma unroll
        for (int i = 0; i < 4; i++) {
            const int qpos = q0 + ty * 4 + i;
#pragma unroll
            for (int jj = 0; jj < 4; jj++) {
                const int kpos = k0 + tx * 4 + jj;
                float val = s[i][jj];
                if (kpos > qpos || mk[tx * 4 + jj] == 0.f) val = FILLV;
                Ss[ty * 4 + i][tx * 4 + jj] = val;
            }
        }
        __syncthreads();

        // online softmax row update (one thread per row)
        if (tid < TQ) {
            const int r = tid;
            const float mOld = mrow[r];
            float mx = mOld;
#pragma unroll 8
            for (int c = 0; c < TK; c++) mx = fmaxf(mx, Ss[r][c]);
            const float al = __expf(mOld - mx);  // exp(-inf) = 0 on first tile
            float sum = 0.f;
#pragma unroll 8
            for (int c = 0; c < TK; c++) {
                const float p = __expf(Ss[r][c] - mx);
                Ss[r][c] = p;
                sum += p;
            }
            mrow[r] = mx;
            lrow[r] = lrow[r] * al + sum;
            arow[r] = al;
        }
        __syncthreads();

        // O update: o[i][:] = o[i][:]*alpha + sum_c p[i][c] * V[c][:]
        float al[4];
#pragma unroll
        for (int i = 0; i < 4; i++) al[i] = arow[ty * 4 + i];
#pragma unroll
        for (int i = 0; i < 4; i++) {
            o[i].x *= al[i]; o[i].y *= al[i]; o[i].z *= al[i]; o[i].w *= al[i];
        }
#pragma unroll
        for (int c4 = 0; c4 < TK; c4 += 4) {
            float4 p0 = *(const float4*)&Ss[ty * 4 + 0][c4];
            float4 p1 = *(const float4*)&Ss[ty * 4 + 1][c4];
            float4 p2 = *(const float4*)&Ss[ty * 4 + 2][c4];
            float4 p3 = *(const float4*)&Ss[ty * 4 + 3][c4];
            float4 v0 = *(const float4*)&Vs[c4 + 0][tx * 4];
            float4 v1 = *(const float4*)&Vs[c4 + 1][tx * 4];
            float4 v2 = *(const float4*)&Vs[c4 + 2][tx * 4];
            float4 v3 = *(const float4*)&Vs[c4 + 3][tx * 4];
            fma4(o[0], p0.x, v0); fma4(o[1], p1.x, v0); fma4(o[2], p2.x, v0); fma4(o[3], p3.x, v0);
            fma4(o[0], p0.y, v1); fma4(o[1], p1.y, v1); fma4(o[2], p2.y, v1); fma4(o[3], p3.y, v1);
            fma4(o[0], p0.z, v2); fma4(o[1], p1.z, v2); fma4(o[2], p2.z, v2); fma4(o[3], p3.z, v2);
            fma4(o[0], p0.w, v3); fma4(o[1], p1.w, v3); fma4(o[2], p2.w, v3); fma4(o[3], p3.w, v3);
        }
    }

    // normalize and store: O[b, q0+r, h*64 + d]
    const size_t baseO = ((size_t)b * SEQ + q0) * HID + (size_t)h * DH;
#pragma unroll
    for (int i = 0; i < 4; i++) {
        const float linv = 1.f / lrow[ty * 4 + i];
        float4 ov = o[i];
        ov.x *= linv; ov.y *= linv; ov.z *= linv; ov.w *= linv;
        *(float4*)&O[baseO + (size_t)(ty * 4 + i) * HID + tx * 4] = ov;
    }
}

// ---------------------------------------------------------------------------
extern "C" void kernel_launch(void* const* d_in, const int* in_sizes, int n_in,
                              void* d_out, int out_size, void* d_ws, size_t ws_size,
                              hipStream_t stream) {
    const float* query = (const float*)d_in[0];
    const float* key   = (const float*)d_in[1];
    const float* value = (const float*)d_in[2];
    const float* mask  = (const float*)d_in[3];
    const float* Wq    = (const float*)d_in[4];
    const float* bq    = (const float*)d_in[5];
    const float* Wk    = (const float*)d_in[6];
    const float* bk    = (const float*)d_in[7];
    const float* Wv    = (const float*)d_in[8];
    const float* bv    = (const float*)d_in[9];
    const float* Wo    = (const float*)d_in[10];
    const float* bo    = (const float*)d_in[11];

    // workspace: Q, K, V, attn-out, each [B*S, H] fp32 (33.5 MB each, 134 MB total)
    const size_t elems = (size_t)MTOT * HID;
    float* Qb = (float*)d_ws;
    float* Kb = Qb + elems;
    float* Vb = Kb + elems;
    float* Ob = Vb + elems;

    dim3 gridG(HID / BN, MTOT / BM);  // (8, 64)
    gemm_nt_bias<<<gridG, 256, 0, stream>>>(query, Wq, bq, Qb, MTOT, HID, HID);
    gemm_nt_bias<<<gridG, 256, 0, stream>>>(key,   Wk, bk, Kb, MTOT, HID, HID);
    gemm_nt_bias<<<gridG, 256, 0, stream>>>(value, Wv, bv, Vb, MTOT, HID, HID);

    dim3 gridA(SEQ / TQ, NH, BATCH);  // (32, 16, 4)
    attn_causal<<<gridA, 256, 0, stream>>>(Qb, Kb, Vb, mask, Ob);

    gemm_nt_bias<<<gridG, 256, 0, stream>>>(Ob, Wo, bo, (float*)d_out, MTOT, HID, HID);
}

// Round 2
// 4306.153 us; speedup vs baseline: 1.3162x; 1.3162x over previous
//
#include <hip/hip_runtime.h>
#include <hip/hip_bf16.h>
#include <math.h>

// Problem constants: B=4, S=2048, H=1024, nh=16, dh=64.
#define BATCH 4
#define SEQ   2048
#define HID   1024
#define NH    16
#define DH    64
#define MTOT  (BATCH * SEQ)   // 8192
#define FILLV (-1e13f)

typedef unsigned short ushort_t;
typedef short bf16x8 __attribute__((ext_vector_type(8)));
typedef float f32x4  __attribute__((ext_vector_type(4)));

__device__ __forceinline__ float bf2f(ushort_t u) {
    return __uint_as_float(((unsigned int)u) << 16);
}
__device__ __forceinline__ ushort_t f2bf(float f) {
    union { __hip_bfloat16 h; ushort_t u; } cv;
    cv.h = __float2bfloat16(f);
    return cv.u;
}

// async global->LDS, 16B per lane; LDS dest = wave-uniform base + lane*16
__device__ __forceinline__ void gload16(const void* g, void* l) {
    __builtin_amdgcn_global_load_lds(
        (const __attribute__((address_space(1))) unsigned int*)g,
        (__attribute__((address_space(3))) unsigned int*)l, 16, 0, 0);
}

// ---------------------------------------------------------------------------
// fp32 -> bf16 cast, 4 elems/thread
// ---------------------------------------------------------------------------
__global__ __launch_bounds__(256) void cast_f32_bf16(
    const float* __restrict__ x, ushort_t* __restrict__ y, int n4)
{
    const int i = blockIdx.x * 256 + threadIdx.x;
    if (i < n4) {
        const float4 v = ((const float4*)x)[i];
        ushort4 o;
        o.x = f2bf(v.x); o.y = f2bf(v.y); o.z = f2bf(v.z); o.w = f2bf(v.w);
        ((ushort4*)y)[i] = o;
    }
}

// ---------------------------------------------------------------------------
// bf16 MFMA GEMM (m97 pattern): Y[M,N] = A[M,K] @ W[N,K]^T + bias
// 128x128 tile, BK=32, 256 threads = 4 waves (2x2 of 64x64), 16x16x32 MFMA.
// LDS in FRAGMENT ORDER: slab s (16 rows x 32 k) stored as 64 lanes x 16B in
// exactly the MFMA operand lane order -> staging via global_load_lds lands
// fragments directly; compute reads are sequential ds_read_b128 (conflict-free).
// A-op layout: lane l holds A[m=l&15][k=(l>>4)*8+j]; B-op symmetric (n=l&15).
// C/D layout (m89-verified): col=lane&15, row=(lane>>4)*4+reg.
// ---------------------------------------------------------------------------
template <bool OUT_BF16>
__global__ __launch_bounds__(256) void gemm_bt_mfma(
    const ushort_t* __restrict__ A,   // [M,K] bf16
    const ushort_t* __restrict__ W,   // [N,K] bf16
    const float*    __restrict__ bias,// [N]  fp32
    void* __restrict__ Yv,            // [M,N] bf16 or fp32
    int M, int N, int K)
{
    __shared__ ushort_t As[8 * 512];  // 8 slabs x 1024B
    __shared__ ushort_t Bs[8 * 512];

    const int tid  = threadIdx.x;
    const int lane = tid & 63;
    const int wave = tid >> 6;
    const int wm   = wave & 1;   // wave row (2x2 wave grid)
    const int wn   = wave >> 1;  // wave col
    const int m0   = blockIdx.y * 128;
    const int n0   = blockIdx.x * 128;
    const int lr   = lane & 15;        // row within slab / frag m-or-n index
    const int lk   = (lane >> 4) * 8;  // k element offset within slab

    // each wave stages slabs {2w, 2w+1} of both A and B (rows w*32 .. w*32+31)
    const ushort_t* aP = A + (size_t)(m0 + wave * 32 + lr) * K + lk;
    const ushort_t* wP = W + (size_t)(n0 + wave * 32 + lr) * K + lk;
    ushort_t* aL = &As[wave * 1024];
    ushort_t* bL = &Bs[wave * 1024];

    f32x4 acc[4][4];
#pragma unroll
    for (int i = 0; i < 4; i++)
#pragma unroll
        for (int j = 0; j < 4; j++) acc[i][j] = (f32x4){0.f, 0.f, 0.f, 0.f};

    for (int k0 = 0; k0 < K; k0 += 32) {
        gload16(aP,          aL);
        gload16(aP + 16 * K, aL + 512);
        gload16(wP,          bL);
        gload16(wP + 16 * K, bL + 512);
        aP += 32; wP += 32;
        __syncthreads();  // drains vmcnt -> staging visible

        bf16x8 af[4], bf[4];
#pragma unroll
        for (int i = 0; i < 4; i++)
            af[i] = *(const bf16x8*)&As[(wm * 4 + i) * 512 + lane * 8];
#pragma unroll
        for (int j = 0; j < 4; j++)
            bf[j] = *(const bf16x8*)&Bs[(wn * 4 + j) * 512 + lane * 8];
#pragma unroll
        for (int i = 0; i < 4; i++)
#pragma unroll
            for (int j = 0; j < 4; j++)
                acc[i][j] = __builtin_amdgcn_mfma_f32_16x16x32_bf16(
                    af[i], bf[j], acc[i][j], 0, 0, 0);
        __syncthreads();  // protect next staging against this iter's reads
    }

    // epilogue
    const int orow = (lane >> 4) * 4;
    const int ocol = lane & 15;
    float bv[4];
#pragma unroll
    for (int j = 0; j < 4; j++) bv[j] = bias[n0 + wn * 64 + j * 16 + ocol];

#pragma unroll
    for (int i = 0; i < 4; i++) {
#pragma unroll
        for (int j = 0; j < 4; j++) {
            const int col = n0 + wn * 64 + j * 16 + ocol;
#pragma unroll
            for (int r = 0; r < 4; r++) {
                const int row = m0 + wm * 64 + i * 16 + orow + r;
                const float v = acc[i][j][r] + bv[j];
                if (OUT_BF16)
                    ((ushort_t*)Yv)[(size_t)row * N + col] = f2bf(v);
                else
                    ((float*)Yv)[(size_t)row * N + col] = v;
            }
        }
    }
}

// ---------------------------------------------------------------------------
// Flash-style causal attention, fp32 VALU, fully-parallel softmax.
// bf16 in (projected Q/K/V as [B*S,H], head h in cols [h*64,h*64+64)), bf16 out.
// Thread (tx=tid&15, ty=tid>>4) owns q-rows {ty+16i}, score-cols {tx+16jj},
// output dims {4tx..4tx+3}. 16-stride ownership makes every hot LDS access
// broadcast or octet-distinct (conflict-free). Softmax row state (m,l)
// replicated across the 16 tx-lanes via __shfl_xor butterflies.
// ---------------------------------------------------------------------------
#define TQ 64
#define TK 64
#define SPAD 68

__device__ __forceinline__ float dot4(const float4 a, const float4 b) {
    return fmaf(a.x, b.x, fmaf(a.y, b.y, fmaf(a.z, b.z, a.w * b.w)));
}
__device__ __forceinline__ void fma4(float4& o, const float p, const float4 v) {
    o.x = fmaf(p, v.x, o.x); o.y = fmaf(p, v.y, o.y);
    o.z = fmaf(p, v.z, o.z); o.w = fmaf(p, v.w, o.w);
}

__global__ __launch_bounds__(256) void attn_causal(
    const ushort_t* __restrict__ Q,
    const ushort_t* __restrict__ Kb,
    const ushort_t* __restrict__ Vb,
    const float*    __restrict__ mask,  // [B,S] over KEY positions
    ushort_t* __restrict__ O)
{
    __shared__ float Qs[TQ][SPAD];
    __shared__ float Ks[TK][SPAD];
    __shared__ float Vs[TK][SPAD];
    __shared__ float Ps[TQ][SPAD];
    __shared__ float mk[TK];

    const int tid = threadIdx.x;
    const int tx  = tid & 15;
    const int ty  = tid >> 4;
    const int qi  = blockIdx.x;
    const int h   = blockIdx.y;
    const int b   = blockIdx.z;
    const int q0  = qi * TQ;
    const float scale = 0.125f;  // 1/sqrt(64)

    // stage Q tile (bf16 -> fp32, pre-scaled)
    const size_t baseQ = ((size_t)b * SEQ + q0) * HID + (size_t)h * DH;
#pragma unroll
    for (int ii = 0; ii < 4; ii++) {
        const int idx = tid + 256 * ii;
        const int r   = idx >> 4;
        const int c4  = (idx & 15) * 4;
        const ushort4 t = *(const ushort4*)&Q[baseQ + (size_t)r * HID + c4];
        float4 f;
        f.x = bf2f(t.x) * scale; f.y = bf2f(t.y) * scale;
        f.z = bf2f(t.z) * scale; f.w = bf2f(t.w) * scale;
        *(float4*)&Qs[r][c4] = f;
    }

    float m_i[4], l_i[4], alpha[4];
#pragma unroll
    for (int i = 0; i < 4; i++) { m_i[i] = -1e30f; l_i[i] = 0.f; }
    float4 o[4];
#pragma unroll
    for (int i = 0; i < 4; i++) o[i] = make_float4(0.f, 0.f, 0.f, 0.f);

    for (int j = 0; j <= qi; j++) {
        const int k0 = j * TK;
        const size_t baseK = ((size_t)b * SEQ + k0) * HID + (size_t)h * DH;

        __syncthreads();  // prior iter's Vs/Ps reads complete (also covers Qs 1st iter)
#pragma unroll
        for (int ii = 0; ii < 4; ii++) {
            const int idx = tid + 256 * ii;
            const int r   = idx >> 4;
            const int c4  = (idx & 15) * 4;
            const ushort4 tk = *(const ushort4*)&Kb[baseK + (size_t)r * HID + c4];
            const ushort4 tv = *(const ushort4*)&Vb[baseK + (size_t)r * HID + c4];
            float4 fk, fv;
            fk.x = bf2f(tk.x); fk.y = bf2f(tk.y); fk.z = bf2f(tk.z); fk.w = bf2f(tk.w);
            fv.x = bf2f(tv.x); fv.y = bf2f(tv.y); fv.z = bf2f(tv.z); fv.w = bf2f(tv.w);
            *(float4*)&Ks[r][c4] = fk;
            *(float4*)&Vs[r][c4] = fv;
        }
        if (tid < TK) mk[tid] = mask[(size_t)b * SEQ + k0 + tid];
        __syncthreads();

        // scores: rows ty+16i, cols tx+16jj
        float s[4][4];
#pragma unroll
        for (int i = 0; i < 4; i++)
#pragma unroll
            for (int jj = 0; jj < 4; jj++) s[i][jj] = 0.f;

#pragma unroll
        for (int k4 = 0; k4 < DH; k4 += 4) {
            float4 qv[4], kv[4];
#pragma unroll
            for (int i = 0; i < 4; i++)  qv[i]  = *(const float4*)&Qs[ty + 16 * i][k4];
#pragma unroll
            for (int jj = 0; jj < 4; jj++) kv[jj] = *(const float4*)&Ks[tx + 16 * jj][k4];
#pragma unroll
            for (int i = 0; i < 4; i++)
#pragma unroll
                for (int jj = 0; jj < 4; jj++)
                    s[i][jj] += dot4(qv[i], kv[jj]);
        }

        // mask + online softmax, parallel across all 256 threads
#pragma unroll
        for (int i = 0; i < 4; i++) {
            const int qpos = q0 + ty + 16 * i;
            float rmax = -1e30f;
#pragma unroll
            for (int jj = 0; jj < 4; jj++) {
                const int kpos = k0 + tx + 16 * jj;
                if (kpos > qpos || mk[tx + 16 * jj] == 0.f) s[i][jj] = FILLV;
                rmax = fmaxf(rmax, s[i][jj]);
            }
#pragma unroll
            for (int d = 1; d < 16; d <<= 1) rmax = fmaxf(rmax, __shfl_xor(rmax, d));
            const float mnew = fmaxf(m_i[i], rmax);
            alpha[i] = __expf(m_i[i] - mnew);
            float rsum = 0.f;
#pragma unroll
            for (int jj = 0; jj < 4; jj++) {
                const float p = __expf(s[i][jj] - mnew);
                Ps[ty + 16 * i][tx + 16 * jj] = p;
                rsum += p;
            }
#pragma unroll
            for (int d = 1; d < 16; d <<= 1) rsum += __shfl_xor(rsum, d);
            m_i[i] = mnew;
            l_i[i] = l_i[i] * alpha[i] + rsum;
        }
        __syncthreads();

        // PV: o[i][4tx..4tx+3] += sum_c P[row_i][c] * V[c][:]
#pragma unroll
        for (int i = 0; i < 4; i++) {
            o[i].x *= alpha[i]; o[i].y *= alpha[i];
            o[i].z *= alpha[i]; o[i].w *= alpha[i];
        }
#pragma unroll
        for (int c4 = 0; c4 < TK; c4 += 4) {
            const float4 p0 = *(const float4*)&Ps[ty +  0][c4];
            const float4 p1 = *(const float4*)&Ps[ty + 16][c4];
            const float4 p2 = *(const float4*)&Ps[ty + 32][c4];
            const float4 p3 = *(const float4*)&Ps[ty + 48][c4];
            const float4 v0 = *(const float4*)&Vs[c4 + 0][tx * 4];
            const float4 v1 = *(const float4*)&Vs[c4 + 1][tx * 4];
            const float4 v2 = *(const float4*)&Vs[c4 + 2][tx * 4];
            const float4 v3 = *(const float4*)&Vs[c4 + 3][tx * 4];
            fma4(o[0], p0.x, v0); fma4(o[0], p0.y, v1); fma4(o[0], p0.z, v2); fma4(o[0], p0.w, v3);
            fma4(o[1], p1.x, v0); fma4(o[1], p1.y, v1); fma4(o[1], p1.z, v2); fma4(o[1], p1.w, v3);
            fma4(o[2], p2.x, v0); fma4(o[2], p2.y, v1); fma4(o[2], p2.z, v2); fma4(o[2], p2.w, v3);
            fma4(o[3], p3.x, v0); fma4(o[3], p3.y, v1); fma4(o[3], p3.z, v2); fma4(o[3], p3.w, v3);
        }
    }

    // normalize + bf16 store: row ty+16i, dims 4tx..4tx+3
    const size_t baseO = ((size_t)b * SEQ + q0) * HID + (size_t)h * DH;
#pragma unroll
    for (int i = 0; i < 4; i++) {
        const float linv = 1.f / l_i[i];
        ushort4 ov;
        ov.x = f2bf(o[i].x * linv); ov.y = f2bf(o[i].y * linv);
        ov.z = f2bf(o[i].z * linv); ov.w = f2bf(o[i].w * linv);
        *(ushort4*)&O[baseO + (size_t)(ty + 16 * i) * HID + tx * 4] = ov;
    }
}

// ---------------------------------------------------------------------------
extern "C" void kernel_launch(void* const* d_in, const int* in_sizes, int n_in,
                              void* d_out, int out_size, void* d_ws, size_t ws_size,
                              hipStream_t stream) {
    const float* query = (const float*)d_in[0];
    const float* key   = (const float*)d_in[1];
    const float* value = (const float*)d_in[2];
    const float* mask  = (const float*)d_in[3];
    const float* Wq    = (const float*)d_in[4];
    const float* bq    = (const float*)d_in[5];
    const float* Wk    = (const float*)d_in[6];
    const float* bk    = (const float*)d_in[7];
    const float* Wv    = (const float*)d_in[8];
    const float* bv    = (const float*)d_in[9];
    const float* Wo    = (const float*)d_in[10];
    const float* bo    = (const float*)d_in[11];

    // workspace (bf16): 7 activation buffers + 4 weight buffers ≈ 125.5 MB
    const size_t eA = (size_t)MTOT * HID;  // 8.4M elems
    const size_t eW = (size_t)HID * HID;   // 1M elems
    ushort_t* qb  = (ushort_t*)d_ws;
    ushort_t* kb  = qb  + eA;
    ushort_t* vb  = kb  + eA;
    ushort_t* Qp  = vb  + eA;
    ushort_t* Kp  = Qp  + eA;
    ushort_t* Vp  = Kp  + eA;
    ushort_t* Op  = Vp  + eA;
    ushort_t* wqb = Op  + eA;
    ushort_t* wkb = wqb + eW;
    ushort_t* wvb = wkb + eW;
    ushort_t* wob = wvb + eW;

    const int n4a = (int)(eA / 4), n4w = (int)(eW / 4);
    cast_f32_bf16<<<(n4a + 255) / 256, 256, 0, stream>>>(query, qb, n4a);
    cast_f32_bf16<<<(n4a + 255) / 256, 256, 0, stream>>>(key,   kb, n4a);
    cast_f32_bf16<<<(n4a + 255) / 256, 256, 0, stream>>>(value, vb, n4a);
    cast_f32_bf16<<<(n4w + 255) / 256, 256, 0, stream>>>(Wq, wqb, n4w);
    cast_f32_bf16<<<(n4w + 255) / 256, 256, 0, stream>>>(Wk, wkb, n4w);
    cast_f32_bf16<<<(n4w + 255) / 256, 256, 0, stream>>>(Wv, wvb, n4w);
    cast_f32_bf16<<<(n4w + 255) / 256, 256, 0, stream>>>(Wo, wob, n4w);

    dim3 gg(HID / 128, MTOT / 128);  // (8, 64)
    gemm_bt_mfma<true><<<gg, 256, 0, stream>>>(qb, wqb, bq, Qp, MTOT, HID, HID);
    gemm_bt_mfma<true><<<gg, 256, 0, stream>>>(kb, wkb, bk, Kp, MTOT, HID, HID);
    gemm_bt_mfma<true><<<gg, 256, 0, stream>>>(vb, wvb, bv, Vp, MTOT, HID, HID);

    dim3 ga(SEQ / TQ, NH, BATCH);  // (32, 16, 4)
    attn_causal<<<ga, 256, 0, stream>>>(Qp, Kp, Vp, mask, Op);

    gemm_bt_mfma<false><<<gg, 256, 0, stream>>>(Op, wob, bo, d_out, MTOT, HID, HID);
}

// Round 4
// 880.638 us; speedup vs baseline: 6.4358x; 4.8898x over previous
//
#include <hip/hip_runtime.h>
#include <hip/hip_bf16.h>
#include <math.h>

// Problem constants: B=4, S=2048, H=1024, nh=16, dh=64.
#define BATCH 4
#define SEQ   2048
#define HID   1024
#define NH    16
#define DH    64
#define MTOT  (BATCH * SEQ)   // 8192
#define FILLV (-1e13f)

typedef unsigned short ushort_t;
typedef short bf16x8 __attribute__((ext_vector_type(8)));
typedef float f32x4  __attribute__((ext_vector_type(4)));

__device__ __forceinline__ float bf2f(ushort_t u) {
    return __uint_as_float(((unsigned int)u) << 16);
}
__device__ __forceinline__ ushort_t f2bf(float f) {
    union { __hip_bfloat16 h; ushort_t u; } cv;
    cv.h = __float2bfloat16(f);
    return cv.u;
}

// async global->LDS, 16B per lane; LDS dest = wave-uniform base + lane*16
__device__ __forceinline__ void gload16(const void* g, void* l) {
    __builtin_amdgcn_global_load_lds(
        (const __attribute__((address_space(1))) unsigned int*)g,
        (__attribute__((address_space(3))) unsigned int*)l, 16, 0, 0);
}

// ---------------------------------------------------------------------------
// fp32 -> bf16 cast, 4 elems/thread
// ---------------------------------------------------------------------------
__global__ __launch_bounds__(256) void cast_f32_bf16(
    const float* __restrict__ x, ushort_t* __restrict__ y, int n4)
{
    const int i = blockIdx.x * 256 + threadIdx.x;
    if (i < n4) {
        const float4 v = ((const float4*)x)[i];
        ushort4 o;
        o.x = f2bf(v.x); o.y = f2bf(v.y); o.z = f2bf(v.z); o.w = f2bf(v.w);
        ((ushort4*)y)[i] = o;
    }
}

// ---------------------------------------------------------------------------
// bf16 MFMA GEMM (m97 pattern): Y[M,N] = A[M,K] @ W[N,K]^T + bias
// 128x128 tile, BK=32, 256 threads = 4 waves (2x2 of 64x64), 16x16x32 MFMA.
// BIAS_ROW=false: bias indexed by output col (normal Linear).
// BIAS_ROW=true:  bias indexed by output row (used for Vt = Wv @ value^T).
// ---------------------------------------------------------------------------
template <bool OUT_BF16, bool BIAS_ROW>
__global__ __launch_bounds__(256) void gemm_bt_mfma(
    const ushort_t* __restrict__ A,   // [M,K] bf16
    const ushort_t* __restrict__ W,   // [N,K] bf16
    const float*    __restrict__ bias,
    void* __restrict__ Yv,            // [M,N] bf16 or fp32
    int M, int N, int K)
{
    __shared__ ushort_t As[8 * 512];  // 8 slabs x 1024B
    __shared__ ushort_t Bs[8 * 512];

    const int tid  = threadIdx.x;
    const int lane = tid & 63;
    const int wave = tid >> 6;
    const int wm   = wave & 1;
    const int wn   = wave >> 1;
    const int m0   = blockIdx.y * 128;
    const int n0   = blockIdx.x * 128;
    const int lr   = lane & 15;
    const int lk   = (lane >> 4) * 8;

    const ushort_t* aP = A + (size_t)(m0 + wave * 32 + lr) * K + lk;
    const ushort_t* wP = W + (size_t)(n0 + wave * 32 + lr) * K + lk;
    ushort_t* aL = &As[wave * 1024];
    ushort_t* bL = &Bs[wave * 1024];

    f32x4 acc[4][4];
#pragma unroll
    for (int i = 0; i < 4; i++)
#pragma unroll
        for (int j = 0; j < 4; j++) acc[i][j] = (f32x4){0.f, 0.f, 0.f, 0.f};

    for (int k0 = 0; k0 < K; k0 += 32) {
        gload16(aP,          aL);
        gload16(aP + 16 * K, aL + 512);
        gload16(wP,          bL);
        gload16(wP + 16 * K, bL + 512);
        aP += 32; wP += 32;
        __syncthreads();

        bf16x8 af[4], bf[4];
#pragma unroll
        for (int i = 0; i < 4; i++)
            af[i] = *(const bf16x8*)&As[(wm * 4 + i) * 512 + lane * 8];
#pragma unroll
        for (int j = 0; j < 4; j++)
            bf[j] = *(const bf16x8*)&Bs[(wn * 4 + j) * 512 + lane * 8];
#pragma unroll
        for (int i = 0; i < 4; i++)
#pragma unroll
            for (int j = 0; j < 4; j++)
                acc[i][j] = __builtin_amdgcn_mfma_f32_16x16x32_bf16(
                    af[i], bf[j], acc[i][j], 0, 0, 0);
        __syncthreads();
    }

    // epilogue; C/D layout: col = lane&15, row = (lane>>4)*4 + reg
    const int orow = (lane >> 4) * 4;
    const int ocol = lane & 15;

#pragma unroll
    for (int i = 0; i < 4; i++) {
#pragma unroll
        for (int j = 0; j < 4; j++) {
            const int col = n0 + wn * 64 + j * 16 + ocol;
#pragma unroll
            for (int r = 0; r < 4; r++) {
                const int row = m0 + wm * 64 + i * 16 + orow + r;
                const float bvv = BIAS_ROW ? bias[row] : bias[col];
                const float v = acc[i][j][r] + bvv;
                if (OUT_BF16)
                    ((ushort_t*)Yv)[(size_t)row * N + col] = f2bf(v);
                else
                    ((float*)Yv)[(size_t)row * N + col] = v;
            }
        }
    }
}

// ---------------------------------------------------------------------------
// MFMA flash attention, zero barriers.
// One WAVE = one (b, h, 16 query rows); 4 independent waves per block.
// Q A-frags persistent in registers; K / Vt B-frags loaded global->reg
// (L2-resident); softmax in registers on C/D layout (row = quad*4+reg,
// col = lane&15) with 16-lane shfl_xor reductions; P transposed C/D -> A-frag
// through a per-wave-private LDS slab (row stride 144 B), no __syncthreads.
// Vt is V transposed per head: Vt[d_global][b*S + s].
// ---------------------------------------------------------------------------
__global__ __launch_bounds__(256) void attn_mfma(
    const ushort_t* __restrict__ Qp,   // [B*S, H]
    const ushort_t* __restrict__ Kp,   // [B*S, H]
    const ushort_t* __restrict__ Vt,   // [H, B*S]
    const float*    __restrict__ mask, // [B, S] over key positions
    ushort_t* __restrict__ Op)         // [B*S, H]
{
    __shared__ ushort_t Pl[4][16 * 72];  // per-wave P: 16 q x 64 keys, stride 72 elems (144 B)

    const int tid  = threadIdx.x;
    const int lane = tid & 63;
    const int wave = tid >> 6;
    const int li   = lane & 15;   // frag m/n index | C/D col
    const int lq   = lane >> 4;   // quad
    const int gw   = blockIdx.x * 4 + wave;
    const int qt   = gw & 127;    // 128 q-tiles of 16 rows
    const int bh   = gw >> 7;     // 0..63
    const int h    = bh & (NH - 1);
    const int b    = bh >> 4;
    const int q0   = qt * 16;
    const int prow = lq * 4;      // this lane's C/D row base

    // persistent Q A-fragments (k-chunks 0,1 of dh=64)
    const size_t qaddr = ((size_t)b * SEQ + q0 + li) * HID + (size_t)h * DH + lq * 8;
    const bf16x8 qf0 = *(const bf16x8*)&Qp[qaddr];
    const bf16x8 qf1 = *(const bf16x8*)&Qp[qaddr + 32];

    f32x4 oa[4];
#pragma unroll
    for (int nt = 0; nt < 4; nt++) oa[nt] = (f32x4){0.f, 0.f, 0.f, 0.f};
    float m_i[4], l_i[4], alpha[4];
#pragma unroll
    for (int r = 0; r < 4; r++) { m_i[r] = -1e30f; l_i[r] = 0.f; }

    const ushort_t* kbase = Kp + ((size_t)b * SEQ + li) * HID + (size_t)h * DH + lq * 8;
    const ushort_t* vbase = Vt + ((size_t)h * DH + li) * MTOT + (size_t)b * SEQ + lq * 8;
    const float*    mbase = mask + (size_t)b * SEQ + li;
    ushort_t* pw = &Pl[wave][0];

    const int jmax = (q0 + 15) >> 6;
    for (int j = 0; j <= jmax; j++) {
        const int k0 = j * 64;

        // ---- S = Q K^T (per 16-key tile nt) ----
        f32x4 sa[4];
#pragma unroll
        for (int nt = 0; nt < 4; nt++) {
            const ushort_t* kp = kbase + (size_t)(k0 + nt * 16) * HID;
            const bf16x8 kf0 = *(const bf16x8*)kp;
            const bf16x8 kf1 = *(const bf16x8*)(kp + 32);
            f32x4 acc = (f32x4){0.f, 0.f, 0.f, 0.f};
            acc = __builtin_amdgcn_mfma_f32_16x16x32_bf16(qf0, kf0, acc, 0, 0, 0);
            acc = __builtin_amdgcn_mfma_f32_16x16x32_bf16(qf1, kf1, acc, 0, 0, 0);
            sa[nt] = acc;
        }

        // ---- scale + mask ----
        float s[4][4];
#pragma unroll
        for (int nt = 0; nt < 4; nt++)
#pragma unroll
            for (int r = 0; r < 4; r++) s[nt][r] = sa[nt][r] * 0.125f;

        if (k0 + 63 > q0) {  // wave-uniform: only diagonal-straddling tiles
#pragma unroll
            for (int nt = 0; nt < 4; nt++) {
                const int kpos = k0 + nt * 16 + li;
#pragma unroll
                for (int r = 0; r < 4; r++)
                    if (kpos > q0 + prow + r) s[nt][r] = FILLV;
            }
        }
#pragma unroll
        for (int nt = 0; nt < 4; nt++) {
            const float mk = mbase[k0 + nt * 16];
            if (mk == 0.f) {
#pragma unroll
                for (int r = 0; r < 4; r++) s[nt][r] = FILLV;
            }
        }

        // ---- online softmax (per C/D row, 16-lane butterflies) ----
#pragma unroll
        for (int r = 0; r < 4; r++) {
            float rmax = fmaxf(fmaxf(s[0][r], s[1][r]), fmaxf(s[2][r], s[3][r]));
            rmax = fmaxf(rmax, __shfl_xor(rmax, 1));
            rmax = fmaxf(rmax, __shfl_xor(rmax, 2));
            rmax = fmaxf(rmax, __shfl_xor(rmax, 4));
            rmax = fmaxf(rmax, __shfl_xor(rmax, 8));
            const float mnew = fmaxf(m_i[r], rmax);
            alpha[r] = __expf(m_i[r] - mnew);
            float psum = 0.f;
#pragma unroll
            for (int nt = 0; nt < 4; nt++) {
                const float p = __expf(s[nt][r] - mnew);
                psum += p;
                pw[(prow + r) * 72 + nt * 16 + li] = f2bf(p);  // P[q][key]
            }
            psum += __shfl_xor(psum, 1);
            psum += __shfl_xor(psum, 2);
            psum += __shfl_xor(psum, 4);
            psum += __shfl_xor(psum, 8);
            m_i[r] = mnew;
            l_i[r] = l_i[r] * alpha[r] + psum;
        }

        // ---- P as A-fragments (same-wave LDS RAW -> compiler lgkmcnt) ----
        const bf16x8 pf0 = *(const bf16x8*)&pw[li * 72 + lq * 8];
        const bf16x8 pf1 = *(const bf16x8*)&pw[li * 72 + 32 + lq * 8];

        // ---- O = alpha*O + P V ----
#pragma unroll
        for (int nt = 0; nt < 4; nt++) {
            const ushort_t* vp = vbase + (size_t)(nt * 16) * MTOT + k0;
            const bf16x8 vf0 = *(const bf16x8*)vp;
            const bf16x8 vf1 = *(const bf16x8*)(vp + 32);
            f32x4 o = oa[nt];
#pragma unroll
            for (int r = 0; r < 4; r++) o[r] *= alpha[r];
            o = __builtin_amdgcn_mfma_f32_16x16x32_bf16(pf0, vf0, o, 0, 0, 0);
            o = __builtin_amdgcn_mfma_f32_16x16x32_bf16(pf1, vf1, o, 0, 0, 0);
            oa[nt] = o;
        }
    }

    // ---- normalize + store bf16 ----
#pragma unroll
    for (int r = 0; r < 4; r++) l_i[r] = 1.f / l_i[r];
    const size_t obase = ((size_t)b * SEQ + q0 + prow) * HID + (size_t)h * DH + li;
#pragma unroll
    for (int nt = 0; nt < 4; nt++)
#pragma unroll
        for (int r = 0; r < 4; r++)
            Op[obase + (size_t)r * HID + nt * 16] = f2bf(oa[nt][r] * l_i[r]);
}

// ---------------------------------------------------------------------------
extern "C" void kernel_launch(void* const* d_in, const int* in_sizes, int n_in,
                              void* d_out, int out_size, void* d_ws, size_t ws_size,
                              hipStream_t stream) {
    const float* query = (const float*)d_in[0];
    const float* key   = (const float*)d_in[1];
    const float* value = (const float*)d_in[2];
    const float* mask  = (const float*)d_in[3];
    const float* Wq    = (const float*)d_in[4];
    const float* bq    = (const float*)d_in[5];
    const float* Wk    = (const float*)d_in[6];
    const float* bk    = (const float*)d_in[7];
    const float* Wv    = (const float*)d_in[8];
    const float* bv    = (const float*)d_in[9];
    const float* Wo    = (const float*)d_in[10];
    const float* bo    = (const float*)d_in[11];

    // workspace (bf16): 7 activation-size buffers + 4 weight buffers ≈ 125.5 MB
    const size_t eA = (size_t)MTOT * HID;
    const size_t eW = (size_t)HID * HID;
    ushort_t* qb  = (ushort_t*)d_ws;
    ushort_t* kb  = qb  + eA;
    ushort_t* vb  = kb  + eA;
    ushort_t* Qp  = vb  + eA;
    ushort_t* Kp  = Qp  + eA;
    ushort_t* Vtb = Kp  + eA;   // [H, B*S]
    ushort_t* Op  = Vtb + eA;
    ushort_t* wqb = Op  + eA;
    ushort_t* wkb = wqb + eW;
    ushort_t* wvb = wkb + eW;
    ushort_t* wob = wvb + eW;

    const int n4a = (int)(eA / 4), n4w = (int)(eW / 4);
    cast_f32_bf16<<<(n4a + 255) / 256, 256, 0, stream>>>(query, qb, n4a);
    cast_f32_bf16<<<(n4a + 255) / 256, 256, 0, stream>>>(key,   kb, n4a);
    cast_f32_bf16<<<(n4a + 255) / 256, 256, 0, stream>>>(value, vb, n4a);
    cast_f32_bf16<<<(n4w + 255) / 256, 256, 0, stream>>>(Wq, wqb, n4w);
    cast_f32_bf16<<<(n4w + 255) / 256, 256, 0, stream>>>(Wk, wkb, n4w);
    cast_f32_bf16<<<(n4w + 255) / 256, 256, 0, stream>>>(Wv, wvb, n4w);
    cast_f32_bf16<<<(n4w + 255) / 256, 256, 0, stream>>>(Wo, wob, n4w);

    dim3 gg(HID / 128, MTOT / 128);   // (8, 64)
    gemm_bt_mfma<true, false><<<gg, 256, 0, stream>>>(qb, wqb, bq, Qp, MTOT, HID, HID);
    gemm_bt_mfma<true, false><<<gg, 256, 0, stream>>>(kb, wkb, bk, Kp, MTOT, HID, HID);
    // Vt = Wv @ value^T  -> [H, B*S], bias by row (bv[d])
    dim3 gv(MTOT / 128, HID / 128);   // (64, 8)
    gemm_bt_mfma<true, true><<<gv, 256, 0, stream>>>(wvb, vb, bv, Vtb, HID, MTOT, HID);

    // flash attention: 8192 independent waves, 4 per block
    attn_mfma<<<(BATCH * NH * 128) / 4, 256, 0, stream>>>(Qp, Kp, Vtb, mask, Op);

    gemm_bt_mfma<false, false><<<gg, 256, 0, stream>>>(Op, wob, bo, d_out, MTOT, HID, HID);
}

// Round 5
// 630.176 us; speedup vs baseline: 8.9937x; 1.3974x over previous
//
#include <hip/hip_runtime.h>
#include <hip/hip_bf16.h>
#include <math.h>

// Problem constants: B=4, S=2048, H=1024, nh=16, dh=64.
#define BATCH 4
#define SEQ   2048
#define HID   1024
#define NH    16
#define DH    64
#define MTOT  (BATCH * SEQ)   // 8192
#define FILLV (-1e13f)

typedef unsigned short ushort_t;
typedef short bf16x8 __attribute__((ext_vector_type(8)));
typedef float f32x4  __attribute__((ext_vector_type(4)));

__device__ __forceinline__ float bf2f(ushort_t u) {
    return __uint_as_float(((unsigned int)u) << 16);
}
__device__ __forceinline__ ushort_t f2bf(float f) {
    union { __hip_bfloat16 h; ushort_t u; } cv;
    cv.h = __float2bfloat16(f);
    return cv.u;
}

// async global->LDS, 16B per lane; LDS dest = wave-uniform base + lane*16
__device__ __forceinline__ void gload16(const void* g, void* l) {
    __builtin_amdgcn_global_load_lds(
        (const __attribute__((address_space(1))) unsigned int*)g,
        (__attribute__((address_space(3))) unsigned int*)l, 16, 0, 0);
}

// ---------------------------------------------------------------------------
// fp32 -> bf16 cast, 4 elems/thread
// ---------------------------------------------------------------------------
__global__ __launch_bounds__(256) void cast_f32_bf16(
    const float* __restrict__ x, ushort_t* __restrict__ y, int n4)
{
    const int i = blockIdx.x * 256 + threadIdx.x;
    if (i < n4) {
        const float4 v = ((const float4*)x)[i];
        ushort4 o;
        o.x = f2bf(v.x); o.y = f2bf(v.y); o.z = f2bf(v.z); o.w = f2bf(v.w);
        ((ushort4*)y)[i] = o;
    }
}

// ---------------------------------------------------------------------------
// bf16 MFMA GEMM (m97 pattern): Y[M,N] = A[M,K] @ W[N,K]^T + bias
// 128x128 tile, BK=32, 256 threads = 4 waves (2x2 of 64x64), 16x16x32 MFMA.
// BIAS_ROW=false: bias indexed by output col (normal Linear).
// BIAS_ROW=true:  bias indexed by output row (used for Vt = Wv @ value^T).
// ---------------------------------------------------------------------------
template <bool OUT_BF16, bool BIAS_ROW>
__global__ __launch_bounds__(256) void gemm_bt_mfma(
    const ushort_t* __restrict__ A,   // [M,K] bf16
    const ushort_t* __restrict__ W,   // [N,K] bf16
    const float*    __restrict__ bias,
    void* __restrict__ Yv,            // [M,N] bf16 or fp32
    int M, int N, int K)
{
    __shared__ ushort_t As[8 * 512];  // 8 slabs x 1024B
    __shared__ ushort_t Bs[8 * 512];

    const int tid  = threadIdx.x;
    const int lane = tid & 63;
    const int wave = tid >> 6;
    const int wm   = wave & 1;
    const int wn   = wave >> 1;
    const int m0   = blockIdx.y * 128;
    const int n0   = blockIdx.x * 128;
    const int lr   = lane & 15;
    const int lk   = (lane >> 4) * 8;

    const ushort_t* aP = A + (size_t)(m0 + wave * 32 + lr) * K + lk;
    const ushort_t* wP = W + (size_t)(n0 + wave * 32 + lr) * K + lk;
    ushort_t* aL = &As[wave * 1024];
    ushort_t* bL = &Bs[wave * 1024];

    f32x4 acc[4][4];
#pragma unroll
    for (int i = 0; i < 4; i++)
#pragma unroll
        for (int j = 0; j < 4; j++) acc[i][j] = (f32x4){0.f, 0.f, 0.f, 0.f};

    for (int k0 = 0; k0 < K; k0 += 32) {
        gload16(aP,          aL);
        gload16(aP + 16 * K, aL + 512);
        gload16(wP,          bL);
        gload16(wP + 16 * K, bL + 512);
        aP += 32; wP += 32;
        __syncthreads();

        bf16x8 af[4], bf[4];
#pragma unroll
        for (int i = 0; i < 4; i++)
            af[i] = *(const bf16x8*)&As[(wm * 4 + i) * 512 + lane * 8];
#pragma unroll
        for (int j = 0; j < 4; j++)
            bf[j] = *(const bf16x8*)&Bs[(wn * 4 + j) * 512 + lane * 8];
#pragma unroll
        for (int i = 0; i < 4; i++)
#pragma unroll
            for (int j = 0; j < 4; j++)
                acc[i][j] = __builtin_amdgcn_mfma_f32_16x16x32_bf16(
                    af[i], bf[j], acc[i][j], 0, 0, 0);
        __syncthreads();
    }

    // epilogue; C/D layout: col = lane&15, row = (lane>>4)*4 + reg
    const int orow = (lane >> 4) * 4;
    const int ocol = lane & 15;

#pragma unroll
    for (int i = 0; i < 4; i++) {
#pragma unroll
        for (int j = 0; j < 4; j++) {
            const int col = n0 + wn * 64 + j * 16 + ocol;
#pragma unroll
            for (int r = 0; r < 4; r++) {
                const int row = m0 + wm * 64 + i * 16 + orow + r;
                const float bvv = BIAS_ROW ? bias[row] : bias[col];
                const float v = acc[i][j][r] + bvv;
                if (OUT_BF16)
                    ((ushort_t*)Yv)[(size_t)row * N + col] = f2bf(v);
                else
                    ((float*)Yv)[(size_t)row * N + col] = v;
            }
        }
    }
}

// ---------------------------------------------------------------------------
// MFMA flash attention, zero barriers, PAIRED q-tiles for uniform wave work.
// One WAVE = one (b, h, PAIR of 16-row q-tiles {pr, 127-pr}) -> every wave
// does ~34 k-tile iterations regardless of pr (kills the causal-triangle
// tail that held round-4 occupancy at 24%). 4 independent waves per block.
// Q A-frags in registers; K / Vt B-frags global->reg (L2-resident); V loads
// hoisted BEFORE softmax so their latency overlaps the shfl/exp chain.
// Softmax in registers on C/D layout (row=quad*4+reg, col=lane&15);
// P transposed C/D -> A-frag via per-wave-private LDS slab. No __syncthreads.
// ---------------------------------------------------------------------------
__global__ __launch_bounds__(256) void attn_mfma(
    const ushort_t* __restrict__ Qp,   // [B*S, H]
    const ushort_t* __restrict__ Kp,   // [B*S, H]
    const ushort_t* __restrict__ Vt,   // [H, B*S]
    const float*    __restrict__ mask, // [B, S] over key positions
    ushort_t* __restrict__ Op)         // [B*S, H]
{
    __shared__ ushort_t Pl[4][16 * 72];  // per-wave P: 16 q x 64 keys, stride 72

    const int tid  = threadIdx.x;
    const int lane = tid & 63;
    const int wave = tid >> 6;
    const int li   = lane & 15;   // frag m/n index | C/D col
    const int lq   = lane >> 4;   // quad
    const int gw   = blockIdx.x * 4 + wave;
    const int pr   = gw & 63;     // pair index: q-tiles {pr, 127-pr}
    const int bh   = gw >> 6;     // 0..63
    const int h    = bh & (NH - 1);
    const int b    = bh >> 4;
    const int prow = lq * 4;      // this lane's C/D row base

    const ushort_t* kbase = Kp + ((size_t)b * SEQ + li) * HID + (size_t)h * DH + lq * 8;
    const ushort_t* vbase = Vt + ((size_t)h * DH + li) * MTOT + (size_t)b * SEQ + lq * 8;
    const float*    mbase = mask + (size_t)b * SEQ + li;
    ushort_t* pw = &Pl[wave][0];

#pragma unroll
    for (int t = 0; t < 2; t++) {
        const int qt = (t == 0) ? pr : (127 - pr);
        const int q0 = qt * 16;

        // persistent Q A-fragments (k-chunks 0,1 of dh=64)
        const size_t qaddr = ((size_t)b * SEQ + q0 + li) * HID + (size_t)h * DH + lq * 8;
        const bf16x8 qf0 = *(const bf16x8*)&Qp[qaddr];
        const bf16x8 qf1 = *(const bf16x8*)&Qp[qaddr + 32];

        f32x4 oa[4];
#pragma unroll
        for (int nt = 0; nt < 4; nt++) oa[nt] = (f32x4){0.f, 0.f, 0.f, 0.f};
        float m_i[4], l_i[4], alpha[4];
#pragma unroll
        for (int r = 0; r < 4; r++) { m_i[r] = -1e30f; l_i[r] = 0.f; }

        const int jmax = q0 >> 6;
        for (int j = 0; j <= jmax; j++) {
            const int k0 = j * 64;

            // ---- S = Q K^T (per 16-key tile nt) ----
            f32x4 sa[4];
#pragma unroll
            for (int nt = 0; nt < 4; nt++) {
                const ushort_t* kp = kbase + (size_t)(k0 + nt * 16) * HID;
                const bf16x8 kf0 = *(const bf16x8*)kp;
                const bf16x8 kf1 = *(const bf16x8*)(kp + 32);
                f32x4 acc = (f32x4){0.f, 0.f, 0.f, 0.f};
                acc = __builtin_amdgcn_mfma_f32_16x16x32_bf16(qf0, kf0, acc, 0, 0, 0);
                acc = __builtin_amdgcn_mfma_f32_16x16x32_bf16(qf1, kf1, acc, 0, 0, 0);
                sa[nt] = acc;
            }

            // ---- hoist V B-frag loads: latency overlaps softmax below ----
            bf16x8 vf[4][2];
#pragma unroll
            for (int nt = 0; nt < 4; nt++) {
                const ushort_t* vp = vbase + (size_t)(nt * 16) * MTOT + k0;
                vf[nt][0] = *(const bf16x8*)vp;
                vf[nt][1] = *(const bf16x8*)(vp + 32);
            }

            // ---- scale + mask ----
            float s[4][4];
#pragma unroll
            for (int nt = 0; nt < 4; nt++)
#pragma unroll
                for (int r = 0; r < 4; r++) s[nt][r] = sa[nt][r] * 0.125f;

            if (k0 + 63 > q0) {  // wave-uniform: diagonal-straddling tiles only
#pragma unroll
                for (int nt = 0; nt < 4; nt++) {
                    const int kpos = k0 + nt * 16 + li;
#pragma unroll
                    for (int r = 0; r < 4; r++)
                        if (kpos > q0 + prow + r) s[nt][r] = FILLV;
                }
            }
#pragma unroll
            for (int nt = 0; nt < 4; nt++) {
                const float mk = mbase[k0 + nt * 16];
                if (mk == 0.f) {
#pragma unroll
                    for (int r = 0; r < 4; r++) s[nt][r] = FILLV;
                }
            }

            // ---- online softmax (per C/D row, 16-lane butterflies) ----
#pragma unroll
            for (int r = 0; r < 4; r++) {
                float rmax = fmaxf(fmaxf(s[0][r], s[1][r]), fmaxf(s[2][r], s[3][r]));
                rmax = fmaxf(rmax, __shfl_xor(rmax, 1));
                rmax = fmaxf(rmax, __shfl_xor(rmax, 2));
                rmax = fmaxf(rmax, __shfl_xor(rmax, 4));
                rmax = fmaxf(rmax, __shfl_xor(rmax, 8));
                const float mnew = fmaxf(m_i[r], rmax);
                alpha[r] = __expf(m_i[r] - mnew);
                float psum = 0.f;
#pragma unroll
                for (int nt = 0; nt < 4; nt++) {
                    const float p = __expf(s[nt][r] - mnew);
                    psum += p;
                    pw[(prow + r) * 72 + nt * 16 + li] = f2bf(p);  // P[q][key]
                }
                psum += __shfl_xor(psum, 1);
                psum += __shfl_xor(psum, 2);
                psum += __shfl_xor(psum, 4);
                psum += __shfl_xor(psum, 8);
                m_i[r] = mnew;
                l_i[r] = l_i[r] * alpha[r] + psum;
            }

            // ---- P as A-fragments (same-wave LDS RAW -> compiler lgkmcnt) ----
            const bf16x8 pf0 = *(const bf16x8*)&pw[li * 72 + lq * 8];
            const bf16x8 pf1 = *(const bf16x8*)&pw[li * 72 + 32 + lq * 8];

            // ---- O = alpha*O + P V ----
#pragma unroll
            for (int nt = 0; nt < 4; nt++) {
                f32x4 o = oa[nt];
#pragma unroll
                for (int r = 0; r < 4; r++) o[r] *= alpha[r];
                o = __builtin_amdgcn_mfma_f32_16x16x32_bf16(pf0, vf[nt][0], o, 0, 0, 0);
                o = __builtin_amdgcn_mfma_f32_16x16x32_bf16(pf1, vf[nt][1], o, 0, 0, 0);
                oa[nt] = o;
            }
        }

        // ---- normalize + store bf16 ----
#pragma unroll
        for (int r = 0; r < 4; r++) l_i[r] = 1.f / l_i[r];
        const size_t obase = ((size_t)b * SEQ + q0 + prow) * HID + (size_t)h * DH + li;
#pragma unroll
        for (int nt = 0; nt < 4; nt++)
#pragma unroll
            for (int r = 0; r < 4; r++)
                Op[obase + (size_t)r * HID + nt * 16] = f2bf(oa[nt][r] * l_i[r]);
    }
}

// ---------------------------------------------------------------------------
extern "C" void kernel_launch(void* const* d_in, const int* in_sizes, int n_in,
                              void* d_out, int out_size, void* d_ws, size_t ws_size,
                              hipStream_t stream) {
    const float* query = (const float*)d_in[0];
    const float* key   = (const float*)d_in[1];
    const float* value = (const float*)d_in[2];
    const float* mask  = (const float*)d_in[3];
    const float* Wq    = (const float*)d_in[4];
    const float* bq    = (const float*)d_in[5];
    const float* Wk    = (const float*)d_in[6];
    const float* bk    = (const float*)d_in[7];
    const float* Wv    = (const float*)d_in[8];
    const float* bv    = (const float*)d_in[9];
    const float* Wo    = (const float*)d_in[10];
    const float* bo    = (const float*)d_in[11];

    // workspace (bf16): 7 activation-size buffers + 4 weight buffers ≈ 125.5 MB
    const size_t eA = (size_t)MTOT * HID;
    const size_t eW = (size_t)HID * HID;
    ushort_t* qb  = (ushort_t*)d_ws;
    ushort_t* kb  = qb  + eA;
    ushort_t* vb  = kb  + eA;
    ushort_t* Qp  = vb  + eA;
    ushort_t* Kp  = Qp  + eA;
    ushort_t* Vtb = Kp  + eA;   // [H, B*S]
    ushort_t* Op  = Vtb + eA;
    ushort_t* wqb = Op  + eA;
    ushort_t* wkb = wqb + eW;
    ushort_t* wvb = wkb + eW;
    ushort_t* wob = wvb + eW;

    const int n4a = (int)(eA / 4), n4w = (int)(eW / 4);
    cast_f32_bf16<<<(n4a + 255) / 256, 256, 0, stream>>>(query, qb, n4a);
    cast_f32_bf16<<<(n4a + 255) / 256, 256, 0, stream>>>(key,   kb, n4a);
    cast_f32_bf16<<<(n4a + 255) / 256, 256, 0, stream>>>(value, vb, n4a);
    cast_f32_bf16<<<(n4w + 255) / 256, 256, 0, stream>>>(Wq, wqb, n4w);
    cast_f32_bf16<<<(n4w + 255) / 256, 256, 0, stream>>>(Wk, wkb, n4w);
    cast_f32_bf16<<<(n4w + 255) / 256, 256, 0, stream>>>(Wv, wvb, n4w);
    cast_f32_bf16<<<(n4w + 255) / 256, 256, 0, stream>>>(Wo, wob, n4w);

    dim3 gg(HID / 128, MTOT / 128);   // (8, 64)
    gemm_bt_mfma<true, false><<<gg, 256, 0, stream>>>(qb, wqb, bq, Qp, MTOT, HID, HID);
    gemm_bt_mfma<true, false><<<gg, 256, 0, stream>>>(kb, wkb, bk, Kp, MTOT, HID, HID);
    // Vt = Wv @ value^T  -> [H, B*S], bias by row (bv[d])
    dim3 gv(MTOT / 128, HID / 128);   // (64, 8)
    gemm_bt_mfma<true, true><<<gv, 256, 0, stream>>>(wvb, vb, bv, Vtb, HID, MTOT, HID);

    // flash attention: 4096 uniform-length waves (paired q-tiles), 4 per block
    attn_mfma<<<(BATCH * NH * 64) / 4, 256, 0, stream>>>(Qp, Kp, Vtb, mask, Op);

    gemm_bt_mfma<false, false><<<gg, 256, 0, stream>>>(Op, wob, bo, d_out, MTOT, HID, HID);
}

// Round 6
// 571.359 us; speedup vs baseline: 9.9196x; 1.1029x over previous
//
#include <hip/hip_runtime.h>
#include <hip/hip_bf16.h>
#include <math.h>

// Problem constants: B=4, S=2048, H=1024, nh=16, dh=64.
#define BATCH 4
#define SEQ   2048
#define HID   1024
#define NH    16
#define DH    64
#define MTOT  (BATCH * SEQ)   // 8192
#define FILLV (-1e13f)

typedef unsigned short ushort_t;
typedef short bf16x8 __attribute__((ext_vector_type(8)));
typedef float f32x4  __attribute__((ext_vector_type(4)));

__device__ __forceinline__ float bf2f(ushort_t u) {
    return __uint_as_float(((unsigned int)u) << 16);
}
__device__ __forceinline__ ushort_t f2bf(float f) {
    union { __hip_bfloat16 h; ushort_t u; } cv;
    cv.h = __float2bfloat16(f);
    return cv.u;
}

// async global->LDS, 16B per lane; LDS dest = wave-uniform base + lane*16
__device__ __forceinline__ void gload16(const void* g, void* l) {
    __builtin_amdgcn_global_load_lds(
        (const __attribute__((address_space(1))) unsigned int*)g,
        (__attribute__((address_space(3))) unsigned int*)l, 16, 0, 0);
}

// ---------------------------------------------------------------------------
// fp32 -> bf16 cast, 4 elems/thread
// ---------------------------------------------------------------------------
__global__ __launch_bounds__(256) void cast_f32_bf16(
    const float* __restrict__ x, ushort_t* __restrict__ y, int n4)
{
    const int i = blockIdx.x * 256 + threadIdx.x;
    if (i < n4) {
        const float4 v = ((const float4*)x)[i];
        ushort4 o;
        o.x = f2bf(v.x); o.y = f2bf(v.y); o.z = f2bf(v.z); o.w = f2bf(v.w);
        ((ushort4*)y)[i] = o;
    }
}

// ---------------------------------------------------------------------------
// bf16 MFMA GEMM (m97 pattern): Y[M,N] = A[M,K] @ W[N,K]^T + bias
// 128x128 tile, BK=32, 256 threads = 4 waves (2x2 of 64x64), 16x16x32 MFMA.
// BIAS_ROW=false: bias indexed by output col (normal Linear).
// BIAS_ROW=true:  bias indexed by output row (used for Vt = Wv @ value^T).
// ---------------------------------------------------------------------------
template <bool OUT_BF16, bool BIAS_ROW>
__global__ __launch_bounds__(256) void gemm_bt_mfma(
    const ushort_t* __restrict__ A,   // [M,K] bf16
    const ushort_t* __restrict__ W,   // [N,K] bf16
    const float*    __restrict__ bias,
    void* __restrict__ Yv,            // [M,N] bf16 or fp32
    int M, int N, int K)
{
    __shared__ ushort_t As[8 * 512];  // 8 slabs x 1024B
    __shared__ ushort_t Bs[8 * 512];

    const int tid  = threadIdx.x;
    const int lane = tid & 63;
    const int wave = tid >> 6;
    const int wm   = wave & 1;
    const int wn   = wave >> 1;
    const int m0   = blockIdx.y * 128;
    const int n0   = blockIdx.x * 128;
    const int lr   = lane & 15;
    const int lk   = (lane >> 4) * 8;

    const ushort_t* aP = A + (size_t)(m0 + wave * 32 + lr) * K + lk;
    const ushort_t* wP = W + (size_t)(n0 + wave * 32 + lr) * K + lk;
    ushort_t* aL = &As[wave * 1024];
    ushort_t* bL = &Bs[wave * 1024];

    f32x4 acc[4][4];
#pragma unroll
    for (int i = 0; i < 4; i++)
#pragma unroll
        for (int j = 0; j < 4; j++) acc[i][j] = (f32x4){0.f, 0.f, 0.f, 0.f};

    for (int k0 = 0; k0 < K; k0 += 32) {
        gload16(aP,          aL);
        gload16(aP + 16 * K, aL + 512);
        gload16(wP,          bL);
        gload16(wP + 16 * K, bL + 512);
        aP += 32; wP += 32;
        __syncthreads();

        bf16x8 af[4], bf[4];
#pragma unroll
        for (int i = 0; i < 4; i++)
            af[i] = *(const bf16x8*)&As[(wm * 4 + i) * 512 + lane * 8];
#pragma unroll
        for (int j = 0; j < 4; j++)
            bf[j] = *(const bf16x8*)&Bs[(wn * 4 + j) * 512 + lane * 8];
#pragma unroll
        for (int i = 0; i < 4; i++)
#pragma unroll
            for (int j = 0; j < 4; j++)
                acc[i][j] = __builtin_amdgcn_mfma_f32_16x16x32_bf16(
                    af[i], bf[j], acc[i][j], 0, 0, 0);
        __syncthreads();
    }

    // epilogue; C/D layout: col = lane&15, row = (lane>>4)*4 + reg
    const int orow = (lane >> 4) * 4;
    const int ocol = lane & 15;

#pragma unroll
    for (int i = 0; i < 4; i++) {
#pragma unroll
        for (int j = 0; j < 4; j++) {
            const int col = n0 + wn * 64 + j * 16 + ocol;
#pragma unroll
            for (int r = 0; r < 4; r++) {
                const int row = m0 + wm * 64 + i * 16 + orow + r;
                const float bvv = BIAS_ROW ? bias[row] : bias[col];
                const float v = acc[i][j][r] + bvv;
                if (OUT_BF16)
                    ((ushort_t*)Yv)[(size_t)row * N + col] = f2bf(v);
                else
                    ((float*)Yv)[(size_t)row * N + col] = v;
            }
        }
    }
}

// ---------------------------------------------------------------------------
// MFMA flash attention, zero barriers, paired q-tiles, XCD-local K/V,
// K-fragment register double-buffer.
//  - One WAVE = (b, h, q-tile pair {pr, 127-pr}) -> uniform ~34 iters/wave.
//  - XCD swizzle: all 16 blocks of one (b,h) land on one XCD (blk&7), so
//    K+V (512 KB/head x 8 heads = 4 MB) stays in that XCD's L2 -> loads are
//    L2 hits, not HBM (round-5: 237 MB fetch = every XCD refetched all K/V).
//  - K B-frags for iteration j+1 issued at top of iteration j (register
//    double-buffer) -> load latency leaves the dependency chain entirely.
//  - V B-frags hoisted before softmax (~400+ cyc overlap, enough for L2).
//  - Softmax in registers on C/D layout (row=quad*4+reg, col=lane&15);
//    P transposed C/D -> A-frag via per-wave-private LDS slab. No barriers.
// ---------------------------------------------------------------------------
__global__ __launch_bounds__(256) void attn_mfma(
    const ushort_t* __restrict__ Qp,   // [B*S, H]
    const ushort_t* __restrict__ Kp,   // [B*S, H]
    const ushort_t* __restrict__ Vt,   // [H, B*S]
    const float*    __restrict__ mask, // [B, S] over key positions
    ushort_t* __restrict__ Op)         // [B*S, H]
{
    __shared__ ushort_t Pl[4][16 * 72];  // per-wave P: 16 q x 64 keys, stride 72

    const int tid  = threadIdx.x;
    const int lane = tid & 63;
    const int wave = tid >> 6;
    const int li   = lane & 15;   // frag m/n index | C/D col
    const int lq   = lane >> 4;   // quad
    const int blk  = blockIdx.x;
    // XCD-aware mapping: xcd = blk&7 (round-robin dispatch), 8 heads per XCD,
    // 16 blocks (pp=0..15) per (b,h), 4 pair-indices per block (one per wave).
    const int xcd = blk & 7;
    const int jj  = blk >> 3;            // 0..127
    const int bh  = xcd * 8 + (jj & 7);  // 0..63
    const int pp  = jj >> 3;             // 0..15
    const int pr  = pp * 4 + wave;       // 0..63: q-tiles {pr, 127-pr}
    const int h   = bh & (NH - 1);
    const int b   = bh >> 4;
    const int prow = lq * 4;      // this lane's C/D row base

    const ushort_t* kbase = Kp + ((size_t)b * SEQ + li) * HID + (size_t)h * DH + lq * 8;
    const ushort_t* vbase = Vt + ((size_t)h * DH + li) * MTOT + (size_t)b * SEQ + lq * 8;
    const float*    mbase = mask + (size_t)b * SEQ + li;
    ushort_t* pw = &Pl[wave][0];

#pragma unroll
    for (int t = 0; t < 2; t++) {
        const int qt = (t == 0) ? pr : (127 - pr);
        const int q0 = qt * 16;

        // persistent Q A-fragments (k-chunks 0,1 of dh=64)
        const size_t qaddr = ((size_t)b * SEQ + q0 + li) * HID + (size_t)h * DH + lq * 8;
        const bf16x8 qf0 = *(const bf16x8*)&Qp[qaddr];
        const bf16x8 qf1 = *(const bf16x8*)&Qp[qaddr + 32];

        f32x4 oa[4];
#pragma unroll
        for (int nt = 0; nt < 4; nt++) oa[nt] = (f32x4){0.f, 0.f, 0.f, 0.f};
        float m_i[4], l_i[4], alpha[4];
#pragma unroll
        for (int r = 0; r < 4; r++) { m_i[r] = -1e30f; l_i[r] = 0.f; }

        const int jmax = q0 >> 6;

        // ---- preload K frags + mask for j=0 ----
        bf16x8 kf[4][2];
        float  mkv[4];
#pragma unroll
        for (int nt = 0; nt < 4; nt++) {
            const ushort_t* kp = kbase + (size_t)(nt * 16) * HID;
            kf[nt][0] = *(const bf16x8*)kp;
            kf[nt][1] = *(const bf16x8*)(kp + 32);
            mkv[nt]   = mbase[nt * 16];
        }

        for (int j = 0; j <= jmax; j++) {
            const int k0 = j * 64;

            // ---- prefetch K frags + mask for j+1 (consumed next iter) ----
            bf16x8 kn[4][2];
            float  mkn[4];
            if (j < jmax) {
                const int k1 = k0 + 64;
#pragma unroll
                for (int nt = 0; nt < 4; nt++) {
                    const ushort_t* kp = kbase + (size_t)(k1 + nt * 16) * HID;
                    kn[nt][0] = *(const bf16x8*)kp;
                    kn[nt][1] = *(const bf16x8*)(kp + 32);
                    mkn[nt]   = mbase[k1 + nt * 16];
                }
            }

            // ---- hoist V B-frag loads: latency overlaps softmax below ----
            bf16x8 vf[4][2];
#pragma unroll
            for (int nt = 0; nt < 4; nt++) {
                const ushort_t* vp = vbase + (size_t)(nt * 16) * MTOT + k0;
                vf[nt][0] = *(const bf16x8*)vp;
                vf[nt][1] = *(const bf16x8*)(vp + 32);
            }

            // ---- S = Q K^T (per 16-key tile nt) ----
            f32x4 sa[4];
#pragma unroll
            for (int nt = 0; nt < 4; nt++) {
                f32x4 acc = (f32x4){0.f, 0.f, 0.f, 0.f};
                acc = __builtin_amdgcn_mfma_f32_16x16x32_bf16(qf0, kf[nt][0], acc, 0, 0, 0);
                acc = __builtin_amdgcn_mfma_f32_16x16x32_bf16(qf1, kf[nt][1], acc, 0, 0, 0);
                sa[nt] = acc;
            }

            // ---- scale + mask ----
            float s[4][4];
#pragma unroll
            for (int nt = 0; nt < 4; nt++)
#pragma unroll
                for (int r = 0; r < 4; r++) s[nt][r] = sa[nt][r] * 0.125f;

            if (k0 + 63 > q0) {  // wave-uniform: diagonal-straddling tiles only
#pragma unroll
                for (int nt = 0; nt < 4; nt++) {
                    const int kpos = k0 + nt * 16 + li;
#pragma unroll
                    for (int r = 0; r < 4; r++)
                        if (kpos > q0 + prow + r) s[nt][r] = FILLV;
                }
            }
#pragma unroll
            for (int nt = 0; nt < 4; nt++) {
                if (mkv[nt] == 0.f) {
#pragma unroll
                    for (int r = 0; r < 4; r++) s[nt][r] = FILLV;
                }
            }

            // ---- online softmax (per C/D row, 16-lane butterflies) ----
#pragma unroll
            for (int r = 0; r < 4; r++) {
                float rmax = fmaxf(fmaxf(s[0][r], s[1][r]), fmaxf(s[2][r], s[3][r]));
                rmax = fmaxf(rmax, __shfl_xor(rmax, 1));
                rmax = fmaxf(rmax, __shfl_xor(rmax, 2));
                rmax = fmaxf(rmax, __shfl_xor(rmax, 4));
                rmax = fmaxf(rmax, __shfl_xor(rmax, 8));
                const float mnew = fmaxf(m_i[r], rmax);
                alpha[r] = __expf(m_i[r] - mnew);
                float psum = 0.f;
#pragma unroll
                for (int nt = 0; nt < 4; nt++) {
                    const float p = __expf(s[nt][r] - mnew);
                    psum += p;
                    pw[(prow + r) * 72 + nt * 16 + li] = f2bf(p);  // P[q][key]
                }
                psum += __shfl_xor(psum, 1);
                psum += __shfl_xor(psum, 2);
                psum += __shfl_xor(psum, 4);
                psum += __shfl_xor(psum, 8);
                m_i[r] = mnew;
                l_i[r] = l_i[r] * alpha[r] + psum;
            }

            // ---- P as A-fragments (same-wave LDS RAW -> compiler lgkmcnt) ----
            const bf16x8 pf0 = *(const bf16x8*)&pw[li * 72 + lq * 8];
            const bf16x8 pf1 = *(const bf16x8*)&pw[li * 72 + 32 + lq * 8];

            // ---- O = alpha*O + P V ----
#pragma unroll
            for (int nt = 0; nt < 4; nt++) {
                f32x4 o = oa[nt];
#pragma unroll
                for (int r = 0; r < 4; r++) o[r] *= alpha[r];
                o = __builtin_amdgcn_mfma_f32_16x16x32_bf16(pf0, vf[nt][0], o, 0, 0, 0);
                o = __builtin_amdgcn_mfma_f32_16x16x32_bf16(pf1, vf[nt][1], o, 0, 0, 0);
                oa[nt] = o;
            }

            // ---- rotate K double-buffer ----
            if (j < jmax) {
#pragma unroll
                for (int nt = 0; nt < 4; nt++) {
                    kf[nt][0] = kn[nt][0];
                    kf[nt][1] = kn[nt][1];
                    mkv[nt]   = mkn[nt];
                }
            }
        }

        // ---- normalize + store bf16 ----
#pragma unroll
        for (int r = 0; r < 4; r++) l_i[r] = 1.f / l_i[r];
        const size_t obase = ((size_t)b * SEQ + q0 + prow) * HID + (size_t)h * DH + li;
#pragma unroll
        for (int nt = 0; nt < 4; nt++)
#pragma unroll
            for (int r = 0; r < 4; r++)
                Op[obase + (size_t)r * HID + nt * 16] = f2bf(oa[nt][r] * l_i[r]);
    }
}

// ---------------------------------------------------------------------------
extern "C" void kernel_launch(void* const* d_in, const int* in_sizes, int n_in,
                              void* d_out, int out_size, void* d_ws, size_t ws_size,
                              hipStream_t stream) {
    const float* query = (const float*)d_in[0];
    const float* key   = (const float*)d_in[1];
    const float* value = (const float*)d_in[2];
    const float* mask  = (const float*)d_in[3];
    const float* Wq    = (const float*)d_in[4];
    const float* bq    = (const float*)d_in[5];
    const float* Wk    = (const float*)d_in[6];
    const float* bk    = (const float*)d_in[7];
    const float* Wv    = (const float*)d_in[8];
    const float* bv    = (const float*)d_in[9];
    const float* Wo    = (const float*)d_in[10];
    const float* bo    = (const float*)d_in[11];

    // workspace (bf16): 7 activation-size buffers + 4 weight buffers ≈ 125.5 MB
    const size_t eA = (size_t)MTOT * HID;
    const size_t eW = (size_t)HID * HID;
    ushort_t* qb  = (ushort_t*)d_ws;
    ushort_t* kb  = qb  + eA;
    ushort_t* vb  = kb  + eA;
    ushort_t* Qp  = vb  + eA;
    ushort_t* Kp  = Qp  + eA;
    ushort_t* Vtb = Kp  + eA;   // [H, B*S]
    ushort_t* Op  = Vtb + eA;
    ushort_t* wqb = Op  + eA;
    ushort_t* wkb = wqb + eW;
    ushort_t* wvb = wkb + eW;
    ushort_t* wob = wvb + eW;

    const int n4a = (int)(eA / 4), n4w = (int)(eW / 4);
    cast_f32_bf16<<<(n4a + 255) / 256, 256, 0, stream>>>(query, qb, n4a);
    cast_f32_bf16<<<(n4a + 255) / 256, 256, 0, stream>>>(key,   kb, n4a);
    cast_f32_bf16<<<(n4a + 255) / 256, 256, 0, stream>>>(value, vb, n4a);
    cast_f32_bf16<<<(n4w + 255) / 256, 256, 0, stream>>>(Wq, wqb, n4w);
    cast_f32_bf16<<<(n4w + 255) / 256, 256, 0, stream>>>(Wk, wkb, n4w);
    cast_f32_bf16<<<(n4w + 255) / 256, 256, 0, stream>>>(Wv, wvb, n4w);
    cast_f32_bf16<<<(n4w + 255) / 256, 256, 0, stream>>>(Wo, wob, n4w);

    dim3 gg(HID / 128, MTOT / 128);   // (8, 64)
    gemm_bt_mfma<true, false><<<gg, 256, 0, stream>>>(qb, wqb, bq, Qp, MTOT, HID, HID);
    gemm_bt_mfma<true, false><<<gg, 256, 0, stream>>>(kb, wkb, bk, Kp, MTOT, HID, HID);
    // Vt = Wv @ value^T  -> [H, B*S], bias by row (bv[d])
    dim3 gv(MTOT / 128, HID / 128);   // (64, 8)
    gemm_bt_mfma<true, true><<<gv, 256, 0, stream>>>(wvb, vb, bv, Vtb, HID, MTOT, HID);

    // flash attention: 4096 uniform waves, XCD-local (b,h), 4 waves/block
    attn_mfma<<<(BATCH * NH * 64) / 4, 256, 0, stream>>>(Qp, Kp, Vtb, mask, Op);

    gemm_bt_mfma<false, false><<<gg, 256, 0, stream>>>(Op, wob, bo, d_out, MTOT, HID, HID);
}